// Round 5
// baseline (267.013 us; speedup 1.0000x reference)
//
#include <hip/hip_runtime.h>
#include <hip/hip_bf16.h>

// ---------------------------------------------------------------------------
// CausalSelfAttention: y = proj( softmax_causal( (xWqkv+b).q @ k^T / 8 ) @ v )
// B=4, T=2048, C=1024, H=16, D=64.  bf16 MFMA compute, fp32 accumulate.
// ---------------------------------------------------------------------------

typedef __attribute__((ext_vector_type(8)))  __bf16 bf16x8;
typedef __attribute__((ext_vector_type(4)))  float  f32x4;
typedef __attribute__((ext_vector_type(16))) float  f32x16;
typedef __attribute__((ext_vector_type(4)))  unsigned int u32x4;

#define AS1C(p) ((const __attribute__((address_space(1))) unsigned int*)(p))
#define AS3(p)  ((__attribute__((address_space(3))) unsigned int*)(p))

__device__ __forceinline__ unsigned short f2bfu(float f){
  __hip_bfloat16 h = __float2bfloat16(f);
  return __builtin_bit_cast(unsigned short, h);
}

// v_permlane32_swap_b32: a.hi(lanes32-63) <-> b.lo(lanes0-31), both modified.
// ONLY safe when a and b hold distinct values (distinct vregs).
__device__ __forceinline__ void plswapu(unsigned int &a, unsigned int &b){
  asm("v_permlane32_swap_b32 %0, %1" : "+v"(a), "+v"(b));
}
// pack two f32 -> one u32 of 2 bf16 (lo = first arg)
__device__ __forceinline__ unsigned int cvtpk(float lo, float hi){
  unsigned int r;
  asm("v_cvt_pk_bf16_f32 %0, %1, %2" : "=v"(r) : "v"(lo), "v"(hi));
  return r;
}

// ---------------- conversion kernels ----------------

__global__ __launch_bounds__(256)
void f32_to_bf16_vec(const float* __restrict__ in, __hip_bfloat16* __restrict__ out, int n4){
  int stride = gridDim.x * blockDim.x;
  for (int i = blockIdx.x*blockDim.x + threadIdx.x; i < n4; i += stride){
    float4 v = reinterpret_cast<const float4*>(in)[i];
    ushort4 u;
    u.x = f2bfu(v.x); u.y = f2bfu(v.y); u.z = f2bfu(v.z); u.w = f2bfu(v.w);
    reinterpret_cast<ushort4*>(out)[i] = u;
  }
}

// in[R][C] fp32 -> out[C][R] bf16
__global__ __launch_bounds__(256)
void transpose_to_bf16(const float* __restrict__ in, __hip_bfloat16* __restrict__ out, int R, int C){
  __shared__ float tile[32][33];
  const int tx = threadIdx.x & 31, ty = threadIdx.x >> 5;
  const int c0 = blockIdx.x*32, r0 = blockIdx.y*32;
  for (int i = ty; i < 32; i += 8)
    tile[i][tx] = in[(size_t)(r0+i)*C + c0 + tx];
  __syncthreads();
  for (int i = ty; i < 32; i += 8)
    out[(size_t)(c0+i)*R + r0 + tx] = __float2bfloat16(tile[tx][i]);
}

// ---------------- bf16 GEMM (m97-style 128x128, BK=32) ----------------

#define QSCALE 0.1803368801111244f   // 0.125 * log2(e) -> softmax in exp2 space

template<int EPI>
__global__ __launch_bounds__(256)
void gemm_bf16(const __hip_bfloat16* __restrict__ A,
               const __hip_bfloat16* __restrict__ Bt,
               const float* __restrict__ bias,
               int M, int N, int K,
               __hip_bfloat16* __restrict__ q_s,
               __hip_bfloat16* __restrict__ k_s,
               __hip_bfloat16* __restrict__ vT_s,
               float* __restrict__ outf)
{
  __shared__ __align__(16) __hip_bfloat16 sA[128*32];
  __shared__ __align__(16) __hip_bfloat16 sB[128*32];
  const int tid = threadIdx.x, w = tid>>6, l = tid&63, g = l>>4, li = l&15;
  const int wm = w>>1, wn = w&1;

  const int nwg = gridDim.x, cpx = nwg >> 3;
  const int swz = (blockIdx.x & 7)*cpx + (blockIdx.x >> 3);
  const int nbx = N >> 7;
  const int m0 = (swz / nbx)*128, n0 = (swz % nbx)*128;

  f32x4 acc[4][4] = {};

  for (int k0 = 0; k0 < K; k0 += 32){
    __syncthreads();
    #pragma unroll
    for (int qq = 0; qq < 2; ++qq){
      const int c = qq*256 + w*64 + l;
      const int row = c>>2, kc = c&3;
      __builtin_amdgcn_global_load_lds(AS1C(A  + (size_t)(m0+row)*K + k0 + 8*kc),
                                       AS3(sA + (qq*256 + w*64)*8), 16, 0, 0);
      __builtin_amdgcn_global_load_lds(AS1C(Bt + (size_t)(n0+row)*K + k0 + 8*kc),
                                       AS3(sB + (qq*256 + w*64)*8), 16, 0, 0);
    }
    __syncthreads();

    bf16x8 af[4], bfr[4];
    #pragma unroll
    for (int mi = 0; mi < 4; ++mi)
      af[mi] = *reinterpret_cast<const bf16x8*>(sA + (wm*64 + mi*16 + li)*32 + 8*g);
    #pragma unroll
    for (int ni = 0; ni < 4; ++ni)
      bfr[ni] = *reinterpret_cast<const bf16x8*>(sB + (wn*64 + ni*16 + li)*32 + 8*g);
    #pragma unroll
    for (int mi = 0; mi < 4; ++mi)
      #pragma unroll
      for (int ni = 0; ni < 4; ++ni)
        acc[mi][ni] = __builtin_amdgcn_mfma_f32_16x16x32_bf16(af[mi], bfr[ni], acc[mi][ni], 0, 0, 0);
  }

  #pragma unroll
  for (int ni = 0; ni < 4; ++ni){
    const int col = n0 + wn*64 + ni*16 + li;
    const float bv = bias[col];
    #pragma unroll
    for (int mi = 0; mi < 4; ++mi){
      #pragma unroll
      for (int e = 0; e < 4; ++e){
        const int row = m0 + wm*64 + mi*16 + 4*g + e;
        const float val = acc[mi][ni][e] + bv;
        if (EPI == 0){
          const int three = col >> 10, h = (col >> 6) & 15, d = col & 63;
          const int b = row >> 11, t = row & 2047;
          const int bh = b*16 + h;
          if (three == 0)      q_s[((size_t)bh*2048 + t)*64 + d]  = __float2bfloat16(val*QSCALE);
          else if (three == 1) k_s[((size_t)bh*2048 + t)*64 + d]  = __float2bfloat16(val);
          else                 vT_s[((size_t)bh*64 + d)*2048 + t] = __float2bfloat16(val);  // V^T
        } else {
          outf[(size_t)row*N + col] = val;
        }
      }
    }
  }
}

// ---------------- flash attention (swapped 32x32 MFMA, in-register softmax) --
// Block = 4 waves; wave w owns 32 q rows (q0 + 32w).  Q-block = 128 rows.
// Pairing: block p of a bh does q-tiles (15-p) then (p): 36 KV tiles each.
// Grid 512 = 64 bh * 8 pairs; bh pinned to XCD bh>>3 (8 bh * 512KB KV = L2).
// KV tile 64, double-buffered; K[kv][64] / VT[d][64kv] XOR-chunk-swizzled.
// QK^T swapped: D[kv][q] (col=q=lane&31) -> softmax per-lane in registers.
// PV swapped:   D[d][q]  (col=q)         -> rescale is a per-lane scalar.
// l accumulated via ones-MFMA (rides the idle MFMA pipe, kills the sum tree).
// Defer-max (THR=8 in log2 space): skip o-rescale unless max grew past THR.

__device__ __forceinline__ void stage_kv(const __hip_bfloat16* __restrict__ k_s,
                                         const __hip_bfloat16* __restrict__ vT_s,
                                         size_t base, int j,
                                         __hip_bfloat16* sk, __hip_bfloat16* svt,
                                         int w, int l)
{
  #pragma unroll
  for (int qq = 0; qq < 2; ++qq){
    const int c = qq*256 + w*64 + l;       // 16B chunk id (512 per 8KB tile)
    const int r = c>>3, cc = c&7;          // 8 chunks per 128B row
    __builtin_amdgcn_global_load_lds(AS1C(k_s  + base + (size_t)(j*64 + r)*64 + 8*(cc ^ (r&7))),
                                     AS3(sk  + (qq*256 + w*64)*8), 16, 0, 0);
    __builtin_amdgcn_global_load_lds(AS1C(vT_s + base + (size_t)r*2048 + j*64 + 8*(cc ^ (r&7))),
                                     AS3(svt + (qq*256 + w*64)*8), 16, 0, 0);
  }
}

__device__ __forceinline__ bf16x8 ldtile(const __hip_bfloat16* t, int row, int chunk){
  return *reinterpret_cast<const bf16x8*>(t + row*64 + ((chunk ^ (row&7))*8));
}

__global__ __launch_bounds__(256)
void flash_attn(const __hip_bfloat16* __restrict__ q_s,
                const __hip_bfloat16* __restrict__ k_s,
                const __hip_bfloat16* __restrict__ vT_s,
                __hip_bfloat16* __restrict__ y_s)
{
  __shared__ __align__(16) __hip_bfloat16 sk [2][64*64];
  __shared__ __align__(16) __hip_bfloat16 svt[2][64*64];

  const int tid = threadIdx.x, w = tid>>6, l = tid&63;
  const int lq = l&31, h = l>>5, h4 = 4*h;
  const int bid = blockIdx.x;
  const int xcd = bid & 7, sl = (bid>>3) & 7, p = bid >> 6;
  const int bh = xcd*8 + sl;
  const size_t base = (size_t)bh * (2048*64);
  const int b = bh >> 4, hh = bh & 15;

  const u32x4 onesu = {0x3F803F80u, 0x3F803F80u, 0x3F803F80u, 0x3F803F80u};
  const bf16x8 onesf = __builtin_bit_cast(bf16x8, onesu);

  #pragma unroll 1
  for (int half = 0; half < 2; ++half){
    const int qbt = half ? p : (15 - p);
    const int q0w = qbt*128 + w*32;
    const int Jmax = 2*qbt + 1;
    const int jd = q0w >> 6;               // diagonal tile for this wave
    const int qabs = q0w + lq;

    bf16x8 qf[4];
    #pragma unroll
    for (int ks = 0; ks < 4; ++ks)
      qf[ks] = *reinterpret_cast<const bf16x8*>(q_s + base + (size_t)qabs*64 + 16*ks + 8*h);

    f32x16 o0 = {}, o1 = {}, lacc = {};
    float mrun = -1e30f;

    __syncthreads();                       // prior half's LDS reads complete
    stage_kv(k_s, vT_s, base, 0, sk[0], svt[0], w, l);
    int cur = 0;

    for (int j = 0; j <= Jmax; ++j){
      __syncthreads();                     // buf[cur] staged
      if (j < Jmax)
        stage_kv(k_s, vT_s, base, j+1, sk[cur^1], svt[cur^1], w, l);

      if (j <= jd){
        // ---- QK^T swapped: St[kv][q], acc s0 = kv 0-31, s1 = kv 32-63 ----
        f32x16 s0 = {}, s1 = {};
        #pragma unroll
        for (int ks = 0; ks < 4; ++ks){
          bf16x8 kf0 = ldtile(sk[cur], lq,      2*ks + h);
          s0 = __builtin_amdgcn_mfma_f32_32x32x16_bf16(kf0, qf[ks], s0, 0, 0, 0);
          bf16x8 kf1 = ldtile(sk[cur], 32 + lq, 2*ks + h);
          s1 = __builtin_amdgcn_mfma_f32_32x32x16_bf16(kf1, qf[ks], s1, 0, 0, 0);
        }

        // ---- in-register online softmax (lane owns q-row qabs) ----
        const bool diag = (j == jd);
        const int rel = qabs - 64*j;
        float pf[32];
        #pragma unroll
        for (int a = 0; a < 2; ++a){
          #pragma unroll
          for (int r = 0; r < 16; ++r){
            float t = (a == 0) ? s0[r] : s1[r];
            if (diag){
              const int kvloc = 32*a + (r&3) + 8*(r>>2) + h4;
              t = (kvloc <= rel) ? t : -1e30f;
            }
            pf[a*16 + r] = t;
          }
        }
        // in-lane max tree over the lane's 32 values
        float a16[16], a8[8], a4[4], a2[2];
        #pragma unroll
        for (int k = 0; k < 16; ++k) a16[k] = fmaxf(pf[k], pf[k+16]);
        #pragma unroll
        for (int k = 0; k < 8; ++k)  a8[k] = fmaxf(a16[k], a16[k+8]);
        #pragma unroll
        for (int k = 0; k < 4; ++k)  a4[k] = fmaxf(a8[k], a8[k+4]);
        a2[0] = fmaxf(a4[0], a4[2]); a2[1] = fmaxf(a4[1], a4[3]);
        float pm = fmaxf(a2[0], a2[1]);

        // defer-max: rescale only if the half-wave max grew past THR=8 (log2)
        if (!__all(pm - mrun <= 8.0f)){
          pm = fmaxf(pm, __shfl_xor(pm, 32));     // combine with partner half
          const float nm = fmaxf(mrun, pm);
          const float corr = exp2f(mrun - nm);
          mrun = nm;
          #pragma unroll
          for (int r = 0; r < 16; ++r){ o0[r] *= corr; o1[r] *= corr; }
          lacc[0] *= corr;                        // only reg 0 of lacc is used
        }

        #pragma unroll
        for (int c = 0; c < 32; ++c) pf[c] = exp2f(pf[c] - mrun);

        // ---- P -> bf16 B-frags (cvt_pk + permlane32_swap, distinct operands) --
        unsigned int wds[16];
        #pragma unroll
        for (int a = 0; a < 2; ++a)
          #pragma unroll
          for (int i = 0; i < 8; ++i)
            wds[a*8 + i] = cvtpk(pf[a*16 + 2*i], pf[a*16 + 2*i + 1]);
        #pragma unroll
        for (int a = 0; a < 2; ++a)
          #pragma unroll
          for (int bl = 0; bl < 2; ++bl){
            plswapu(wds[a*8 + 4*bl    ], wds[a*8 + 4*bl + 2]);
            plswapu(wds[a*8 + 4*bl + 1], wds[a*8 + 4*bl + 3]);
          }
        bf16x8 pfr[4];
        #pragma unroll
        for (int B = 0; B < 4; ++B){
          u32x4 t = { wds[4*B], wds[4*B+1], wds[4*B+2], wds[4*B+3] };
          pfr[B] = __builtin_bit_cast(bf16x8, t);
        }

        // ---- PV swapped: O[d][q] + l via ones-MFMA (colsum of P) ----
        #pragma unroll
        for (int ks = 0; ks < 4; ++ks){
          bf16x8 vf0 = ldtile(svt[cur], lq,      2*ks + h);
          o0 = __builtin_amdgcn_mfma_f32_32x32x16_bf16(vf0, pfr[ks], o0, 0, 0, 0);
          bf16x8 vf1 = ldtile(svt[cur], 32 + lq, 2*ks + h);
          o1 = __builtin_amdgcn_mfma_f32_32x32x16_bf16(vf1, pfr[ks], o1, 0, 0, 0);
          lacc = __builtin_amdgcn_mfma_f32_32x32x16_bf16(onesf, pfr[ks], lacc, 0, 0, 0);
        }
      }
      cur ^= 1;
    }

    // ---- epilogue: y[b*2048 + q][hh*64 + d]; l = lacc[0] (same for any row) --
    const float inv = 1.f / lacc[0];
    __hip_bfloat16* yp = y_s + ((size_t)(b*2048 + qabs))*1024 + hh*64;
    #pragma unroll
    for (int i = 0; i < 8; ++i){
      const int d = (2*i & 3) + 8*(i>>1) + h4;     // r=2i -> (r&3)+8*(r>>2)+4h
      *reinterpret_cast<unsigned int*>(yp + d)      = cvtpk(o0[2*i]*inv, o0[2*i+1]*inv);
      *reinterpret_cast<unsigned int*>(yp + 32 + d) = cvtpk(o1[2*i]*inv, o1[2*i+1]*inv);
    }
  }
}

// ---------------- launch ----------------

extern "C" void kernel_launch(void* const* d_in, const int* in_sizes, int n_in,
                              void* d_out, int out_size, void* d_ws, size_t ws_size,
                              hipStream_t stream)
{
  const float* x      = (const float*)d_in[0];
  const float* w_attn = (const float*)d_in[1];
  const float* b_attn = (const float*)d_in[2];
  const float* w_proj = (const float*)d_in[3];
  const float* b_proj = (const float*)d_in[4];
  float* out = (float*)d_out;
  char* ws = (char*)d_ws;

  __hip_bfloat16* xb     = (__hip_bfloat16*)(ws + 0);          // 16 MB [8192][1024]
  __hip_bfloat16* wattnT = (__hip_bfloat16*)(ws + 16777216);   //  6 MB [3072][1024]
  __hip_bfloat16* wprojT = (__hip_bfloat16*)(ws + 23068672);   //  2 MB [1024][1024]
  __hip_bfloat16* q_s    = (__hip_bfloat16*)(ws + 25165824);   // 16 MB [64bh][2048][64]
  __hip_bfloat16* k_s    = (__hip_bfloat16*)(ws + 41943040);   // 16 MB [64bh][2048][64]
  __hip_bfloat16* vT_s   = (__hip_bfloat16*)(ws + 58720256);   // 16 MB [64bh][64][2048]
  __hip_bfloat16* y_s    = xb;                                  // reuse xb after gemm1

  f32_to_bf16_vec<<<2048, 256, 0, stream>>>(x, xb, 8388608/4);
  transpose_to_bf16<<<dim3(3072/32, 1024/32), 256, 0, stream>>>(w_attn, wattnT, 1024, 3072);
  transpose_to_bf16<<<dim3(1024/32, 1024/32), 256, 0, stream>>>(w_proj, wprojT, 1024, 1024);

  gemm_bf16<0><<<1536, 256, 0, stream>>>(
      xb, wattnT, b_attn, 8192, 3072, 1024, q_s, k_s, vT_s, (float*)nullptr);

  flash_attn<<<512, 256, 0, stream>>>(q_s, k_s, vT_s, y_s);

  gemm_bf16<1><<<512, 256, 0, stream>>>(
      y_s, wprojT, b_proj, 8192, 1024, 1024,
      (__hip_bfloat16*)nullptr, (__hip_bfloat16*)nullptr, (__hip_bfloat16*)nullptr, out);
}

// Round 6
// 225.553 us; speedup vs baseline: 1.1838x; 1.1838x over previous
//
#include <hip/hip_runtime.h>
#include <hip/hip_bf16.h>

// ---------------------------------------------------------------------------
// CausalSelfAttention: y = proj( softmax_causal( (xWqkv+b).q @ k^T / 8 ) @ v )
// B=4, T=2048, C=1024, H=16, D=64.  bf16 MFMA compute, fp32 accumulate.
// ---------------------------------------------------------------------------

typedef __attribute__((ext_vector_type(8)))  __bf16 bf16x8;
typedef __attribute__((ext_vector_type(4)))  float  f32x4;
typedef __attribute__((ext_vector_type(16))) float  f32x16;
typedef __attribute__((ext_vector_type(4)))  unsigned int u32x4;

#define AS1C(p) ((const __attribute__((address_space(1))) unsigned int*)(p))
#define AS3(p)  ((__attribute__((address_space(3))) unsigned int*)(p))

__device__ __forceinline__ unsigned short f2bfu(float f){
  __hip_bfloat16 h = __float2bfloat16(f);
  return __builtin_bit_cast(unsigned short, h);
}

// v_permlane32_swap_b32: a.hi(lanes32-63) <-> b.lo(lanes0-31), both modified.
// ONLY safe when a and b hold distinct values (distinct vregs).
__device__ __forceinline__ void plswapu(unsigned int &a, unsigned int &b){
  asm("v_permlane32_swap_b32 %0, %1" : "+v"(a), "+v"(b));
}
// pack two f32 -> one u32 of 2 bf16 (lo = first arg)
__device__ __forceinline__ unsigned int cvtpk(float lo, float hi){
  unsigned int r;
  asm("v_cvt_pk_bf16_f32 %0, %1, %2" : "=v"(r) : "v"(lo), "v"(hi));
  return r;
}

// ---------------- conversion kernels ----------------

__global__ __launch_bounds__(256)
void f32_to_bf16_vec(const float* __restrict__ in, __hip_bfloat16* __restrict__ out, int n4){
  int stride = gridDim.x * blockDim.x;
  for (int i = blockIdx.x*blockDim.x + threadIdx.x; i < n4; i += stride){
    float4 v = reinterpret_cast<const float4*>(in)[i];
    ushort4 u;
    u.x = f2bfu(v.x); u.y = f2bfu(v.y); u.z = f2bfu(v.z); u.w = f2bfu(v.w);
    reinterpret_cast<ushort4*>(out)[i] = u;
  }
}

// in[R][C] fp32 -> out[C][R] bf16
__global__ __launch_bounds__(256)
void transpose_to_bf16(const float* __restrict__ in, __hip_bfloat16* __restrict__ out, int R, int C){
  __shared__ float tile[32][33];
  const int tx = threadIdx.x & 31, ty = threadIdx.x >> 5;
  const int c0 = blockIdx.x*32, r0 = blockIdx.y*32;
  for (int i = ty; i < 32; i += 8)
    tile[i][tx] = in[(size_t)(r0+i)*C + c0 + tx];
  __syncthreads();
  for (int i = ty; i < 32; i += 8)
    out[(size_t)(c0+i)*R + r0 + tx] = __float2bfloat16(tile[tx][i]);
}

// ---------------- bf16 GEMM (m97-style 128x128, BK=32) ----------------

#define QSCALE 0.1803368801111244f   // 0.125 * log2(e) -> softmax in exp2 space

template<int EPI>
__global__ __launch_bounds__(256)
void gemm_bf16(const __hip_bfloat16* __restrict__ A,
               const __hip_bfloat16* __restrict__ Bt,
               const float* __restrict__ bias,
               int M, int N, int K,
               __hip_bfloat16* __restrict__ q_s,
               __hip_bfloat16* __restrict__ k_s,
               __hip_bfloat16* __restrict__ vT_s,
               float* __restrict__ outf)
{
  __shared__ __align__(16) __hip_bfloat16 sA[128*32];
  __shared__ __align__(16) __hip_bfloat16 sB[128*32];
  const int tid = threadIdx.x, w = tid>>6, l = tid&63, g = l>>4, li = l&15;
  const int wm = w>>1, wn = w&1;

  const int nwg = gridDim.x, cpx = nwg >> 3;
  const int swz = (blockIdx.x & 7)*cpx + (blockIdx.x >> 3);
  const int nbx = N >> 7;
  const int m0 = (swz / nbx)*128, n0 = (swz % nbx)*128;

  f32x4 acc[4][4] = {};

  for (int k0 = 0; k0 < K; k0 += 32){
    __syncthreads();
    #pragma unroll
    for (int qq = 0; qq < 2; ++qq){
      const int c = qq*256 + w*64 + l;
      const int row = c>>2, kc = c&3;
      __builtin_amdgcn_global_load_lds(AS1C(A  + (size_t)(m0+row)*K + k0 + 8*kc),
                                       AS3(sA + (qq*256 + w*64)*8), 16, 0, 0);
      __builtin_amdgcn_global_load_lds(AS1C(Bt + (size_t)(n0+row)*K + k0 + 8*kc),
                                       AS3(sB + (qq*256 + w*64)*8), 16, 0, 0);
    }
    __syncthreads();

    bf16x8 af[4], bfr[4];
    #pragma unroll
    for (int mi = 0; mi < 4; ++mi)
      af[mi] = *reinterpret_cast<const bf16x8*>(sA + (wm*64 + mi*16 + li)*32 + 8*g);
    #pragma unroll
    for (int ni = 0; ni < 4; ++ni)
      bfr[ni] = *reinterpret_cast<const bf16x8*>(sB + (wn*64 + ni*16 + li)*32 + 8*g);
    #pragma unroll
    for (int mi = 0; mi < 4; ++mi)
      #pragma unroll
      for (int ni = 0; ni < 4; ++ni)
        acc[mi][ni] = __builtin_amdgcn_mfma_f32_16x16x32_bf16(af[mi], bfr[ni], acc[mi][ni], 0, 0, 0);
  }

  #pragma unroll
  for (int ni = 0; ni < 4; ++ni){
    const int col = n0 + wn*64 + ni*16 + li;
    const float bv = bias[col];
    #pragma unroll
    for (int mi = 0; mi < 4; ++mi){
      #pragma unroll
      for (int e = 0; e < 4; ++e){
        const int row = m0 + wm*64 + mi*16 + 4*g + e;
        const float val = acc[mi][ni][e] + bv;
        if (EPI == 0){
          const int three = col >> 10, h = (col >> 6) & 15, d = col & 63;
          const int b = row >> 11, t = row & 2047;
          const int bh = b*16 + h;
          if (three == 0)      q_s[((size_t)bh*2048 + t)*64 + d]  = __float2bfloat16(val*QSCALE);
          else if (three == 1) k_s[((size_t)bh*2048 + t)*64 + d]  = __float2bfloat16(val);
          else                 vT_s[((size_t)bh*64 + d)*2048 + t] = __float2bfloat16(val);  // V^T
        } else {
          outf[(size_t)row*N + col] = val;
        }
      }
    }
  }
}

// ---------------- flash attention (swapped 32x32 MFMA, in-register softmax) --
// Block = 4 waves; wave w owns 32 q rows (q0 + 32w).  Q-block = 128 rows.
// Pairing: block p of a bh does q-tiles (15-p) then (p): 36 KV tiles each.
// Grid 512 = 64 bh * 8 pairs; bh pinned to XCD bh>>3 (8 bh * 512KB KV = L2).
// KV tile 64, double-buffered; K[kv][64] / VT[d][64kv] XOR-chunk-swizzled.
// QK^T swapped: D[kv][q] (col=q=lane&31) -> softmax per-lane in registers.
// PV swapped:   D[d][q]  (col=q)         -> rescale is a per-lane scalar.
// Defer-max (THR=8 in log2 space): skip o-rescale unless max grew past THR.

__device__ __forceinline__ void stage_kv(const __hip_bfloat16* __restrict__ k_s,
                                         const __hip_bfloat16* __restrict__ vT_s,
                                         size_t base, int j,
                                         __hip_bfloat16* sk, __hip_bfloat16* svt,
                                         int w, int l)
{
  #pragma unroll
  for (int qq = 0; qq < 2; ++qq){
    const int c = qq*256 + w*64 + l;       // 16B chunk id (512 per 8KB tile)
    const int r = c>>3, cc = c&7;          // 8 chunks per 128B row
    __builtin_amdgcn_global_load_lds(AS1C(k_s  + base + (size_t)(j*64 + r)*64 + 8*(cc ^ (r&7))),
                                     AS3(sk  + (qq*256 + w*64)*8), 16, 0, 0);
    __builtin_amdgcn_global_load_lds(AS1C(vT_s + base + (size_t)r*2048 + j*64 + 8*(cc ^ (r&7))),
                                     AS3(svt + (qq*256 + w*64)*8), 16, 0, 0);
  }
}

__device__ __forceinline__ bf16x8 ldtile(const __hip_bfloat16* t, int row, int chunk){
  return *reinterpret_cast<const bf16x8*>(t + row*64 + ((chunk ^ (row&7))*8));
}

__global__ __launch_bounds__(256)
void flash_attn(const __hip_bfloat16* __restrict__ q_s,
                const __hip_bfloat16* __restrict__ k_s,
                const __hip_bfloat16* __restrict__ vT_s,
                __hip_bfloat16* __restrict__ y_s)
{
  __shared__ __align__(16) __hip_bfloat16 sk [2][64*64];
  __shared__ __align__(16) __hip_bfloat16 svt[2][64*64];

  const int tid = threadIdx.x, w = tid>>6, l = tid&63;
  const int lq = l&31, h = l>>5, h4 = 4*h;
  const int bid = blockIdx.x;
  const int xcd = bid & 7, sl = (bid>>3) & 7, p = bid >> 6;
  const int bh = xcd*8 + sl;
  const size_t base = (size_t)bh * (2048*64);
  const int b = bh >> 4, hh = bh & 15;

  #pragma unroll 1
  for (int half = 0; half < 2; ++half){
    const int qbt = half ? p : (15 - p);
    const int q0w = qbt*128 + w*32;
    const int Jmax = 2*qbt + 1;
    const int jd = q0w >> 6;               // diagonal tile for this wave
    const int qabs = q0w + lq;

    bf16x8 qf[4];
    #pragma unroll
    for (int ks = 0; ks < 4; ++ks)
      qf[ks] = *reinterpret_cast<const bf16x8*>(q_s + base + (size_t)qabs*64 + 16*ks + 8*h);

    f32x16 o0 = {}, o1 = {};
    float mrun = -1e30f, lrun = 0.f;

    __syncthreads();                       // prior half's LDS reads complete
    stage_kv(k_s, vT_s, base, 0, sk[0], svt[0], w, l);
    int cur = 0;

    for (int j = 0; j <= Jmax; ++j){
      __syncthreads();                     // buf[cur] staged
      if (j < Jmax)
        stage_kv(k_s, vT_s, base, j+1, sk[cur^1], svt[cur^1], w, l);

      if (j <= jd){
        // ---- QK^T swapped: St[kv][q], acc s0 = kv 0-31, s1 = kv 32-63 ----
        f32x16 s0 = {}, s1 = {};
        #pragma unroll
        for (int ks = 0; ks < 4; ++ks){
          bf16x8 kf0 = ldtile(sk[cur], lq,      2*ks + h);
          s0 = __builtin_amdgcn_mfma_f32_32x32x16_bf16(kf0, qf[ks], s0, 0, 0, 0);
          bf16x8 kf1 = ldtile(sk[cur], 32 + lq, 2*ks + h);
          s1 = __builtin_amdgcn_mfma_f32_32x32x16_bf16(kf1, qf[ks], s1, 0, 0, 0);
        }

        // ---- in-register online softmax (lane owns q-row qabs) ----
        const bool diag = (j == jd);
        const int rel = qabs - 64*j;
        float pf[32];
        #pragma unroll
        for (int a = 0; a < 2; ++a){
          #pragma unroll
          for (int r = 0; r < 16; ++r){
            float t = (a == 0) ? s0[r] : s1[r];
            if (diag){
              const int kvloc = 32*a + (r&3) + 8*(r>>2) + h4;
              t = (kvloc <= rel) ? t : -1e30f;
            }
            pf[a*16 + r] = t;
          }
        }
        // in-lane max tree over the lane's 32 values
        float a16[16], a8[8], a4[4], a2[2];
        #pragma unroll
        for (int k = 0; k < 16; ++k) a16[k] = fmaxf(pf[k], pf[k+16]);
        #pragma unroll
        for (int k = 0; k < 8; ++k)  a8[k] = fmaxf(a16[k], a16[k+8]);
        #pragma unroll
        for (int k = 0; k < 4; ++k)  a4[k] = fmaxf(a8[k], a8[k+4]);
        a2[0] = fmaxf(a4[0], a4[2]); a2[1] = fmaxf(a4[1], a4[3]);
        float pm = fmaxf(a2[0], a2[1]);

        // defer-max (T13): rescale only if half-wave max grew past THR=8 (log2)
        if (!__all(pm - mrun <= 8.0f)){
          pm = fmaxf(pm, __shfl_xor(pm, 32));     // combine with partner half
          const float nm = fmaxf(mrun, pm);
          const float corr = exp2f(mrun - nm);
          mrun = nm;
          #pragma unroll
          for (int r = 0; r < 16; ++r){ o0[r] *= corr; o1[r] *= corr; }
          lrun *= corr;
        }

        #pragma unroll
        for (int c = 0; c < 32; ++c) pf[c] = exp2f(pf[c] - mrun);

        // in-lane sum tree + cross-half combine
        float b16[16], b8[8], b4[4];
        #pragma unroll
        for (int k = 0; k < 16; ++k) b16[k] = pf[k] + pf[k+16];
        #pragma unroll
        for (int k = 0; k < 8; ++k)  b8[k] = b16[k] + b16[k+8];
        #pragma unroll
        for (int k = 0; k < 4; ++k)  b4[k] = b8[k] + b8[k+4];
        float psum = (b4[0]+b4[1]) + (b4[2]+b4[3]);
        psum += __shfl_xor(psum, 32);
        lrun += psum;

        // ---- P -> bf16 B-frags (cvt_pk + permlane32_swap, distinct operands) --
        unsigned int wds[16];
        #pragma unroll
        for (int a = 0; a < 2; ++a)
          #pragma unroll
          for (int i = 0; i < 8; ++i)
            wds[a*8 + i] = cvtpk(pf[a*16 + 2*i], pf[a*16 + 2*i + 1]);
        #pragma unroll
        for (int a = 0; a < 2; ++a)
          #pragma unroll
          for (int bl = 0; bl < 2; ++bl){
            plswapu(wds[a*8 + 4*bl    ], wds[a*8 + 4*bl + 2]);
            plswapu(wds[a*8 + 4*bl + 1], wds[a*8 + 4*bl + 3]);
          }
        bf16x8 pfr[4];
        #pragma unroll
        for (int B = 0; B < 4; ++B){
          u32x4 t = { wds[4*B], wds[4*B+1], wds[4*B+2], wds[4*B+3] };
          pfr[B] = __builtin_bit_cast(bf16x8, t);
        }

        // ---- PV swapped: O[d][q], acc o0 = d 0-31, o1 = d 32-63 ----
        #pragma unroll
        for (int ks = 0; ks < 4; ++ks){
          bf16x8 vf0 = ldtile(svt[cur], lq,      2*ks + h);
          o0 = __builtin_amdgcn_mfma_f32_32x32x16_bf16(vf0, pfr[ks], o0, 0, 0, 0);
          bf16x8 vf1 = ldtile(svt[cur], 32 + lq, 2*ks + h);
          o1 = __builtin_amdgcn_mfma_f32_32x32x16_bf16(vf1, pfr[ks], o1, 0, 0, 0);
        }
      }
      cur ^= 1;
    }

    // ---- epilogue: y[b*2048 + q][hh*64 + d] ----
    const float inv = 1.f / lrun;
    __hip_bfloat16* yp = y_s + ((size_t)(b*2048 + qabs))*1024 + hh*64;
    #pragma unroll
    for (int i = 0; i < 8; ++i){
      const int d = (2*i & 3) + 8*(i>>1) + h4;     // r=2i -> (r&3)+8*(r>>2)+4h
      *reinterpret_cast<unsigned int*>(yp + d)      = cvtpk(o0[2*i]*inv, o0[2*i+1]*inv);
      *reinterpret_cast<unsigned int*>(yp + 32 + d) = cvtpk(o1[2*i]*inv, o1[2*i+1]*inv);
    }
  }
}

// ---------------- launch ----------------

extern "C" void kernel_launch(void* const* d_in, const int* in_sizes, int n_in,
                              void* d_out, int out_size, void* d_ws, size_t ws_size,
                              hipStream_t stream)
{
  const float* x      = (const float*)d_in[0];
  const float* w_attn = (const float*)d_in[1];
  const float* b_attn = (const float*)d_in[2];
  const float* w_proj = (const float*)d_in[3];
  const float* b_proj = (const float*)d_in[4];
  float* out = (float*)d_out;
  char* ws = (char*)d_ws;

  __hip_bfloat16* xb     = (__hip_bfloat16*)(ws + 0);          // 16 MB [8192][1024]
  __hip_bfloat16* wattnT = (__hip_bfloat16*)(ws + 16777216);   //  6 MB [3072][1024]
  __hip_bfloat16* wprojT = (__hip_bfloat16*)(ws + 23068672);   //  2 MB [1024][1024]
  __hip_bfloat16* q_s    = (__hip_bfloat16*)(ws + 25165824);   // 16 MB [64bh][2048][64]
  __hip_bfloat16* k_s    = (__hip_bfloat16*)(ws + 41943040);   // 16 MB [64bh][2048][64]
  __hip_bfloat16* vT_s   = (__hip_bfloat16*)(ws + 58720256);   // 16 MB [64bh][64][2048]
  __hip_bfloat16* y_s    = xb;                                  // reuse xb after gemm1

  f32_to_bf16_vec<<<2048, 256, 0, stream>>>(x, xb, 8388608/4);
  transpose_to_bf16<<<dim3(3072/32, 1024/32), 256, 0, stream>>>(w_attn, wattnT, 1024, 3072);
  transpose_to_bf16<<<dim3(1024/32, 1024/32), 256, 0, stream>>>(w_proj, wprojT, 1024, 1024);

  gemm_bf16<0><<<1536, 256, 0, stream>>>(
      xb, wattnT, b_attn, 8192, 3072, 1024, q_s, k_s, vT_s, (float*)nullptr);

  flash_attn<<<512, 256, 0, stream>>>(q_s, k_s, vT_s, y_s);

  gemm_bf16<1><<<512, 256, 0, stream>>>(
      y_s, wprojT, b_proj, 8192, 1024, 1024,
      (__hip_bfloat16*)nullptr, (__hip_bfloat16*)nullptr, (__hip_bfloat16*)nullptr, out);
}